// Round 1
// baseline (312.284 us; speedup 1.0000x reference)
//
#include <hip/hip_runtime.h>

#define D 1024
#define KOUT 128
#define BM 64
#define BK 32

// ---------------- Kernel A: colsum[j] = sum_b e1[b,j]*e2[b,j] ----------------
__global__ __launch_bounds__(256) void colsum_kernel(
    const float* __restrict__ e1, const float* __restrict__ e2,
    float* __restrict__ colsum, int rows_per_block) {
    int tid = threadIdx.x;                 // 0..255 -> float4 column index (256*4 = 1024 cols)
    long r0 = (long)blockIdx.x * rows_per_block;
    const float4* e1v = (const float4*)e1;
    const float4* e2v = (const float4*)e2;
    const int cols4 = D / 4;               // 256
    float4 s = {0.f, 0.f, 0.f, 0.f};
    for (int r = 0; r < rows_per_block; ++r) {
        long idx = (r0 + r) * cols4 + tid;
        float4 a = e1v[idx];
        float4 b = e2v[idx];
        s.x += a.x * b.x;
        s.y += a.y * b.y;
        s.z += a.z * b.z;
        s.w += a.w * b.w;
    }
    atomicAdd(&colsum[tid * 4 + 0], s.x);
    atomicAdd(&colsum[tid * 4 + 1], s.y);
    atomicAdd(&colsum[tid * 4 + 2], s.z);
    atomicAdd(&colsum[tid * 4 + 3], s.w);
}

// ---------------- Kernel B: dvec[i] = b[i] + (1/(d*B)) * sum_j W[i,j]*colsum[j] ----
__global__ __launch_bounds__(256) void diag_kernel(
    const float* __restrict__ W, const float* __restrict__ bias,
    const float* __restrict__ colsum, float* __restrict__ dvec, float inv_scale) {
    int i = blockIdx.x;
    int tid = threadIdx.x;
    float s = 0.f;
    for (int j = tid; j < D; j += 256) s += W[i * D + j] * colsum[j];
    // wave64 reduce
    #pragma unroll
    for (int off = 32; off > 0; off >>= 1) s += __shfl_down(s, off, 64);
    __shared__ float wsum[4];
    if ((tid & 63) == 0) wsum[tid >> 6] = s;
    __syncthreads();
    if (tid == 0)
        dvec[i] = bias[i] + (wsum[0] + wsum[1] + wsum[2] + wsum[3]) * inv_scale;
}

// ---------------- Kernel C: out = tanh([e1|e2] @ V + dvec) ----------------
// 256 threads; tx = tid&31 (cols, 4 each), ty = tid>>5 (rows, 8 each).
// Within a wave64 only 2 distinct ty -> A-fragment LDS reads are 2-way
// broadcast (free); V reads are consecutive 16B/lane (conflict-free).
__global__ __launch_bounds__(256) void gemm_tanh_kernel(
    const float* __restrict__ e1, const float* __restrict__ e2,
    const float* __restrict__ V, const float* __restrict__ dvec,
    float* __restrict__ out) {
    __shared__ float At[BM][BK];       // 8 KB
    __shared__ float Vt[BK][KOUT];     // 16 KB
    __shared__ float dv[KOUT];

    int tid = threadIdx.x;
    int tx = tid & 31;
    int ty = tid >> 5;
    long m0 = (long)blockIdx.x * BM;

    if (tid < KOUT) dv[tid] = dvec[tid];

    float acc[8][4];
    #pragma unroll
    for (int r = 0; r < 8; ++r)
        #pragma unroll
        for (int c = 0; c < 4; ++c) acc[r][c] = 0.f;

    int lane8 = tid & 7;       // which 16B chunk of the 32-float K-slice
    int rbase = tid >> 3;      // 0..31

    for (int k0 = 0; k0 < 2 * D; k0 += BK) {
        // ---- stage A tile: rows [m0, m0+64), cols [k0, k0+32) of concat(e1,e2)
        const float* src = (k0 < D) ? e1 : e2;
        int kc = (k0 < D) ? k0 : (k0 - D);
        #pragma unroll
        for (int p = 0; p < 2; ++p) {
            int row = rbase + p * 32;
            float4 v = *(const float4*)&src[(m0 + row) * D + kc + lane8 * 4];
            *(float4*)&At[row][lane8 * 4] = v;
        }
        // ---- stage V tile: [k0, k0+32) x 128  (1024 float4, 4 per thread)
        #pragma unroll
        for (int p = 0; p < 4; ++p) {
            int f = p * 256 + tid;         // float4 index in tile
            int vr = f >> 5;               // 0..31
            int vc4 = f & 31;              // 0..31
            float4 v = *(const float4*)&V[(long)(k0 + vr) * KOUT + vc4 * 4];
            *(float4*)&Vt[vr][vc4 * 4] = v;
        }
        __syncthreads();

        // ---- inner product: 8 rows x 4 cols per thread, K-vectorized by 4
        #pragma unroll
        for (int kk = 0; kk < BK; kk += 4) {
            float4 av[8];
            #pragma unroll
            for (int r = 0; r < 8; ++r)
                av[r] = *(const float4*)&At[ty * 8 + r][kk];
            float4 vv[4];
            #pragma unroll
            for (int q = 0; q < 4; ++q)
                vv[q] = *(const float4*)&Vt[kk + q][tx * 4];
            #pragma unroll
            for (int r = 0; r < 8; ++r) {
                const float* ap = (const float*)&av[r];
                #pragma unroll
                for (int q = 0; q < 4; ++q) {
                    float a = ap[q];
                    acc[r][0] += a * vv[q].x;
                    acc[r][1] += a * vv[q].y;
                    acc[r][2] += a * vv[q].z;
                    acc[r][3] += a * vv[q].w;
                }
            }
        }
        __syncthreads();
    }

    // ---- epilogue: + dvec, tanh, coalesced float4 store
    float d0 = dv[tx * 4 + 0], d1 = dv[tx * 4 + 1];
    float d2 = dv[tx * 4 + 2], d3 = dv[tx * 4 + 3];
    #pragma unroll
    for (int r = 0; r < 8; ++r) {
        long row = m0 + ty * 8 + r;
        float4 o;
        o.x = tanhf(acc[r][0] + d0);
        o.y = tanhf(acc[r][1] + d1);
        o.z = tanhf(acc[r][2] + d2);
        o.w = tanhf(acc[r][3] + d3);
        *(float4*)&out[row * KOUT + tx * 4] = o;
    }
}

extern "C" void kernel_launch(void* const* d_in, const int* in_sizes, int n_in,
                              void* d_out, int out_size, void* d_ws, size_t ws_size,
                              hipStream_t stream) {
    const float* e1 = (const float*)d_in[0];
    const float* e2 = (const float*)d_in[1];
    const float* W  = (const float*)d_in[2];
    const float* V  = (const float*)d_in[3];
    const float* b  = (const float*)d_in[4];
    float* out = (float*)d_out;

    int B = in_sizes[0] / D;               // 32768

    float* colsum = (float*)d_ws;          // [D]
    float* dvec   = colsum + D;            // [KOUT]

    hipMemsetAsync(colsum, 0, D * sizeof(float), stream);

    const int rows_per_block = 128;
    colsum_kernel<<<B / rows_per_block, 256, 0, stream>>>(e1, e2, colsum, rows_per_block);
    diag_kernel<<<KOUT, 256, 0, stream>>>(W, b, colsum, dvec,
                                          1.0f / ((float)D * (float)B));
    gemm_tanh_kernel<<<B / BM, 256, 0, stream>>>(e1, e2, V, dvec, out);
}

// Round 2
// 285.319 us; speedup vs baseline: 1.0945x; 1.0945x over previous
//
#include <hip/hip_runtime.h>

#define D 1024
#define KOUT 128
#define KTOT 2048   // 2*D

typedef __attribute__((ext_vector_type(8))) __bf16 bf16x8;
typedef __attribute__((ext_vector_type(4))) float f32x4;

// ---------------- Kernel A: colsum[j] = sum_b e1[b,j]*e2[b,j] ----------------
__global__ __launch_bounds__(256) void colsum_kernel(
    const float* __restrict__ e1, const float* __restrict__ e2,
    float* __restrict__ colsum, int rows_per_block) {
    int tid = threadIdx.x;                 // float4 column index (256*4 = 1024 cols)
    long r0 = (long)blockIdx.x * rows_per_block;
    const float4* e1v = (const float4*)e1;
    const float4* e2v = (const float4*)e2;
    const int cols4 = D / 4;               // 256
    float4 s = {0.f, 0.f, 0.f, 0.f};
    for (int r = 0; r < rows_per_block; ++r) {
        long idx = (r0 + r) * cols4 + tid;
        float4 a = e1v[idx];
        float4 b = e2v[idx];
        s.x += a.x * b.x;
        s.y += a.y * b.y;
        s.z += a.z * b.z;
        s.w += a.w * b.w;
    }
    atomicAdd(&colsum[tid * 4 + 0], s.x);
    atomicAdd(&colsum[tid * 4 + 1], s.y);
    atomicAdd(&colsum[tid * 4 + 2], s.z);
    atomicAdd(&colsum[tid * 4 + 3], s.w);
}

// ---------------- Kernel B: dvec[i] = b[i] + (1/(d*B)) * sum_j W[i,j]*colsum[j] ----
__global__ __launch_bounds__(256) void diag_kernel(
    const float* __restrict__ W, const float* __restrict__ bias,
    const float* __restrict__ colsum, float* __restrict__ dvec, float inv_scale) {
    int i = blockIdx.x;
    int tid = threadIdx.x;
    float s = 0.f;
    for (int j = tid; j < D; j += 256) s += W[i * D + j] * colsum[j];
    #pragma unroll
    for (int off = 32; off > 0; off >>= 1) s += __shfl_down(s, off, 64);
    __shared__ float wsum[4];
    if ((tid & 63) == 0) wsum[tid >> 6] = s;
    __syncthreads();
    if (tid == 0)
        dvec[i] = bias[i] + (wsum[0] + wsum[1] + wsum[2] + wsum[3]) * inv_scale;
}

// ---------------- Kernel V: split V into bf16 hi/lo, transposed to [n][k] ----
__global__ __launch_bounds__(256) void vconv_kernel(
    const float* __restrict__ V, __bf16* __restrict__ hi, __bf16* __restrict__ lo) {
    int idx = blockIdx.x * 256 + threadIdx.x;   // 0 .. 2048*128-1, linear over V[k][n]
    int k = idx >> 7;
    int n = idx & 127;
    float x = V[idx];
    __bf16 h = (__bf16)x;
    __bf16 l = (__bf16)(x - (float)h);
    hi[(long)n * KTOT + k] = h;
    lo[(long)n * KTOT + k] = l;
}

// ---------------- Kernel C: out = tanh([e1|e2] @ V + dvec), bf16-split MFMA ----
// 256 threads = 4 waves; wave handles 32 rows x 128 cols.
// A fragment (16x16x32 bf16): lane l holds A[row=l&15][k=(l>>4)*8 + j], j=0..7.
// B fragment: lane l holds B[k=(l>>4)*8+j][col=l&15]  -> contiguous in Vt[n][k].
// D fragment: col = lane&15, row = (lane>>4)*4 + reg.
__global__ __launch_bounds__(256, 1) void mfma_gemm_tanh(
    const float* __restrict__ e1, const float* __restrict__ e2,
    const __bf16* __restrict__ Vt_hi, const __bf16* __restrict__ Vt_lo,
    const float* __restrict__ dvec, float* __restrict__ out) {
    int tid  = threadIdx.x;
    int wave = tid >> 6;
    int lane = tid & 63;
    int lrow = lane & 15;
    int lk   = lane >> 4;                  // 0..3
    long m0  = (long)blockIdx.x * 128 + wave * 32;

    f32x4 acc[2][8] = {};

    // ---- prologue: load A raw fp32 for k0 = 0
    float4 a_raw[2][2][2];                 // [buf][rt][half]
    #pragma unroll
    for (int rt = 0; rt < 2; ++rt) {
        const float* p = e1 + (m0 + rt * 16 + lrow) * D + lk * 8;
        a_raw[0][rt][0] = *(const float4*)p;
        a_raw[0][rt][1] = *(const float4*)(p + 4);
    }

    for (int k0 = 0; k0 < KTOT; k0 += 32) {
        int cur = (k0 >> 5) & 1;
        int nxt = cur ^ 1;

        // ---- B fragments first (L2-resident, ~200cy) : 8 col-tiles, hi+lo
        bf16x8 bh[8], bl[8];
        #pragma unroll
        for (int ct = 0; ct < 8; ++ct) {
            long boff = (long)(ct * 16 + lrow) * KTOT + k0 + lk * 8;
            bh[ct] = *(const bf16x8*)(Vt_hi + boff);
            bl[ct] = *(const bf16x8*)(Vt_lo + boff);
        }

        // ---- prefetch next K-step's A raw (HBM latency hides under MFMAs)
        if (k0 + 32 < KTOT) {
            int k1 = k0 + 32;
            const float* src = (k1 < D) ? e1 : e2;
            int kc = (k1 & (D - 1)) + lk * 8;
            #pragma unroll
            for (int rt = 0; rt < 2; ++rt) {
                const float* p = src + (m0 + rt * 16 + lrow) * D + kc;
                a_raw[nxt][rt][0] = *(const float4*)p;
                a_raw[nxt][rt][1] = *(const float4*)(p + 4);
            }
        }

        // ---- convert current A raw -> bf16 hi/lo fragments
        bf16x8 ah[2], al[2];
        #pragma unroll
        for (int rt = 0; rt < 2; ++rt) {
            float xs[8];
            xs[0] = a_raw[cur][rt][0].x; xs[1] = a_raw[cur][rt][0].y;
            xs[2] = a_raw[cur][rt][0].z; xs[3] = a_raw[cur][rt][0].w;
            xs[4] = a_raw[cur][rt][1].x; xs[5] = a_raw[cur][rt][1].y;
            xs[6] = a_raw[cur][rt][1].z; xs[7] = a_raw[cur][rt][1].w;
            #pragma unroll
            for (int j = 0; j < 8; ++j) {
                __bf16 h = (__bf16)xs[j];
                ah[rt][j] = h;
                al[rt][j] = (__bf16)(xs[j] - (float)h);
            }
        }

        // ---- 3 passes, pass-major so consecutive MFMAs hit different acc
        #pragma unroll
        for (int ct = 0; ct < 8; ++ct)
            #pragma unroll
            for (int rt = 0; rt < 2; ++rt)
                acc[rt][ct] = __builtin_amdgcn_mfma_f32_16x16x32_bf16(
                    ah[rt], bh[ct], acc[rt][ct], 0, 0, 0);
        #pragma unroll
        for (int ct = 0; ct < 8; ++ct)
            #pragma unroll
            for (int rt = 0; rt < 2; ++rt)
                acc[rt][ct] = __builtin_amdgcn_mfma_f32_16x16x32_bf16(
                    ah[rt], bl[ct], acc[rt][ct], 0, 0, 0);
        #pragma unroll
        for (int ct = 0; ct < 8; ++ct)
            #pragma unroll
            for (int rt = 0; rt < 2; ++rt)
                acc[rt][ct] = __builtin_amdgcn_mfma_f32_16x16x32_bf16(
                    al[rt], bh[ct], acc[rt][ct], 0, 0, 0);
    }

    // ---- epilogue: + dvec, tanh, store
    #pragma unroll
    for (int ct = 0; ct < 8; ++ct) {
        float dv = dvec[ct * 16 + lrow];
        #pragma unroll
        for (int rt = 0; rt < 2; ++rt) {
            #pragma unroll
            for (int v = 0; v < 4; ++v) {
                long row = m0 + rt * 16 + lk * 4 + v;
                out[row * KOUT + ct * 16 + lrow] = tanhf(acc[rt][ct][v] + dv);
            }
        }
    }
}

extern "C" void kernel_launch(void* const* d_in, const int* in_sizes, int n_in,
                              void* d_out, int out_size, void* d_ws, size_t ws_size,
                              hipStream_t stream) {
    const float* e1 = (const float*)d_in[0];
    const float* e2 = (const float*)d_in[1];
    const float* W  = (const float*)d_in[2];
    const float* V  = (const float*)d_in[3];
    const float* b  = (const float*)d_in[4];
    float* out = (float*)d_out;

    int B = in_sizes[0] / D;               // 32768

    float* colsum = (float*)d_ws;                    // [1024]
    float* dvec   = colsum + D;                      // [128]
    __bf16* Vt_hi = (__bf16*)((char*)d_ws + 4608);   // [128][2048] bf16, 16B aligned
    __bf16* Vt_lo = (__bf16*)((char*)d_ws + 4608 + (size_t)KOUT * KTOT * 2);

    hipMemsetAsync(colsum, 0, D * sizeof(float), stream);

    vconv_kernel<<<(KTOT * KOUT) / 256, 256, 0, stream>>>(V, Vt_hi, Vt_lo);

    const int rows_per_block = 128;
    colsum_kernel<<<B / rows_per_block, 256, 0, stream>>>(e1, e2, colsum, rows_per_block);
    diag_kernel<<<KOUT, 256, 0, stream>>>(W, b, colsum, dvec,
                                          1.0f / ((float)D * (float)B));
    mfma_gemm_tanh<<<B / 128, 256, 0, stream>>>(e1, e2, Vt_hi, Vt_lo, dvec, out);
}

// Round 3
// 165.087 us; speedup vs baseline: 1.8916x; 1.7283x over previous
//
#include <hip/hip_runtime.h>
#include <stdint.h>

#define D 1024
#define KOUT 128
#define KTOT 2048
#define BM 64
#define NSTEPS 64

typedef __attribute__((ext_vector_type(8))) __bf16 bf16x8;
typedef __attribute__((ext_vector_type(4))) float f32x4;

// ---------------- Kernel A: colsum[j] = sum_b e1[b,j]*e2[b,j] ----------------
__global__ __launch_bounds__(256) void colsum_kernel(
    const float* __restrict__ e1, const float* __restrict__ e2,
    float* __restrict__ colsum, int rows_per_block) {
    int tid = threadIdx.x;
    long r0 = (long)blockIdx.x * rows_per_block;
    const float4* e1v = (const float4*)e1;
    const float4* e2v = (const float4*)e2;
    const int cols4 = D / 4;
    float4 s = {0.f, 0.f, 0.f, 0.f};
    for (int r = 0; r < rows_per_block; ++r) {
        long idx = (r0 + r) * cols4 + tid;
        float4 a = e1v[idx];
        float4 b = e2v[idx];
        s.x += a.x * b.x;
        s.y += a.y * b.y;
        s.z += a.z * b.z;
        s.w += a.w * b.w;
    }
    atomicAdd(&colsum[tid * 4 + 0], s.x);
    atomicAdd(&colsum[tid * 4 + 1], s.y);
    atomicAdd(&colsum[tid * 4 + 2], s.z);
    atomicAdd(&colsum[tid * 4 + 3], s.w);
}

// ---------------- Kernel B: dvec[i] = b[i] + (1/(d*B)) * sum_j W[i,j]*colsum[j]
__global__ __launch_bounds__(256) void diag_kernel(
    const float* __restrict__ W, const float* __restrict__ bias,
    const float* __restrict__ colsum, float* __restrict__ dvec, float inv_scale) {
    int i = blockIdx.x;
    int tid = threadIdx.x;
    float s = 0.f;
    for (int j = tid; j < D; j += 256) s += W[i * D + j] * colsum[j];
    #pragma unroll
    for (int off = 32; off > 0; off >>= 1) s += __shfl_down(s, off, 64);
    __shared__ float wsum[4];
    if ((tid & 63) == 0) wsum[tid >> 6] = s;
    __syncthreads();
    if (tid == 0)
        dvec[i] = bias[i] + (wsum[0] + wsum[1] + wsum[2] + wsum[3]) * inv_scale;
}

// ---------------- Kernel V: build staging-ready, pre-swizzled hi/lo split of V
// Vstage[kstep 0..63][16384 bytes]: per n-row (128 rows): [hi k0..31 | lo k0..31],
// row byte-offset XOR'd with ((n&7)<<4). Linear global_load_lds of one 16KB
// chunk then yields the swizzled LDS layout directly.
__global__ __launch_bounds__(256) void vconv_kernel(
    const float* __restrict__ V, char* __restrict__ Vstage) {
    int idx = blockIdx.x * 256 + threadIdx.x;   // over 2048*128 elements of V[k][n]
    int k = idx >> 7;
    int n = idx & 127;
    float x = V[idx];
    __bf16 h = (__bf16)x;
    __bf16 l = (__bf16)(x - (float)h);
    int kstep = k >> 5;
    int kk = k & 31;
    uint32_t sw = ((uint32_t)(n & 7)) << 4;
    uint32_t oh = (uint32_t)(n * 128 + kk * 2);
    char* base = Vstage + (size_t)kstep * 16384;
    *(__bf16*)(base + (oh ^ sw)) = h;
    *(__bf16*)(base + ((oh + 64) ^ sw)) = l;
}

// ---------------- Kernel C: out = tanh([e1|e2] @ V + dvec), LDS-staged MFMA ----
// 256 threads = 4 waves; tile M=64 x N=128, BK=32; wave w owns rows w*16..w*16+15.
// A: [64 rows][128B fp32] XOR-swizzled; B: [128 n][hi 64B | lo 64B] XOR-swizzled.
__global__ __launch_bounds__(256) void mfma_gemm_tanh(
    const float* __restrict__ e1, const float* __restrict__ e2,
    const char* __restrict__ Vstage, const float* __restrict__ dvec,
    float* __restrict__ out) {
    __shared__ char As[2][8192];
    __shared__ char Bs[2][16384];

    int tid  = threadIdx.x;
    int wave = tid >> 6;
    int lane = tid & 63;
    int lrow = lane & 15;
    int lk   = lane >> 4;                  // 0..3
    long m0  = (long)blockIdx.x * BM;

    f32x4 acc[8];
    #pragma unroll
    for (int ct = 0; ct < 8; ++ct) acc[ct] = (f32x4){0.f, 0.f, 0.f, 0.f};

    // ---- staging: A via pre-swizzled per-lane global source; B linear copy
    auto stage = [&](int s, int buf) {
        const float* src = (s < 32) ? e1 : e2;
        int kc = (s & 31) * 32;            // float column offset
        #pragma unroll
        for (int r = 0; r < 2; ++r) {
            uint32_t slot = (uint32_t)(r * 4096 + tid * 16);
            uint32_t row  = slot >> 7;
            uint32_t o    = slot ^ ((row & 7u) << 4);
            const char* g = (const char*)src + (((long)(m0 + row)) << 12)
                            + (kc << 2) + (o & 127u);
            char* l = &As[buf][r * 4096 + wave * 1024];
            __builtin_amdgcn_global_load_lds(
                (const __attribute__((address_space(1))) uint32_t*)g,
                (__attribute__((address_space(3))) uint32_t*)l, 16, 0, 0);
        }
        const char* gb = Vstage + (size_t)s * 16384;
        #pragma unroll
        for (int r = 0; r < 4; ++r) {
            const char* g = gb + r * 4096 + tid * 16;
            char* l = &Bs[buf][r * 4096 + wave * 1024];
            __builtin_amdgcn_global_load_lds(
                (const __attribute__((address_space(1))) uint32_t*)g,
                (__attribute__((address_space(3))) uint32_t*)l, 16, 0, 0);
        }
    };

    stage(0, 0);
    __syncthreads();

    uint32_t arow = (uint32_t)(wave * 16 + lrow);
    uint32_t asw  = (arow & 7u) << 4;
    uint32_t aoff = (uint32_t)(arow * 128 + lk * 32);
    uint32_t a0off = (aoff) ^ asw;
    uint32_t a1off = (aoff + 16) ^ asw;

    for (int s = 0; s < NSTEPS; ++s) {
        int cur = s & 1;
        if (s + 1 < NSTEPS) stage(s + 1, cur ^ 1);

        const char* ab = &As[cur][0];
        f32x4 a0 = *(const f32x4*)(ab + a0off);
        f32x4 a1 = *(const f32x4*)(ab + a1off);

        bf16x8 ah, al;
        #pragma unroll
        for (int j = 0; j < 4; ++j) {
            float x = a0[j];
            __bf16 h = (__bf16)x;
            ah[j] = h;
            al[j] = (__bf16)(x - (float)h);
            float y = a1[j];
            __bf16 h2 = (__bf16)y;
            ah[4 + j] = h2;
            al[4 + j] = (__bf16)(y - (float)h2);
        }

        const char* bb = &Bs[cur][0];
        #pragma unroll
        for (int ct = 0; ct < 8; ++ct) {
            uint32_t n = (uint32_t)(ct * 16 + lrow);
            uint32_t boff = (n * 128 + (uint32_t)(lk * 16)) ^ ((n & 7u) << 4);
            bf16x8 bh = *(const bf16x8*)(bb + boff);
            bf16x8 bl = *(const bf16x8*)(bb + (boff ^ 64u));
            acc[ct] = __builtin_amdgcn_mfma_f32_16x16x32_bf16(ah, bh, acc[ct], 0, 0, 0);
            acc[ct] = __builtin_amdgcn_mfma_f32_16x16x32_bf16(al, bh, acc[ct], 0, 0, 0);
            acc[ct] = __builtin_amdgcn_mfma_f32_16x16x32_bf16(ah, bl, acc[ct], 0, 0, 0);
        }
        __syncthreads();
    }

    // ---- epilogue: + dvec, tanh, store (D frag: col=lane&15, row=(lane>>4)*4+v)
    #pragma unroll
    for (int ct = 0; ct < 8; ++ct) {
        float dv = dvec[ct * 16 + lrow];
        #pragma unroll
        for (int v = 0; v < 4; ++v) {
            long row = m0 + wave * 16 + lk * 4 + v;
            out[row * KOUT + ct * 16 + lrow] = tanhf(acc[ct][v] + dv);
        }
    }
}

extern "C" void kernel_launch(void* const* d_in, const int* in_sizes, int n_in,
                              void* d_out, int out_size, void* d_ws, size_t ws_size,
                              hipStream_t stream) {
    const float* e1 = (const float*)d_in[0];
    const float* e2 = (const float*)d_in[1];
    const float* W  = (const float*)d_in[2];
    const float* V  = (const float*)d_in[3];
    const float* b  = (const float*)d_in[4];
    float* out = (float*)d_out;

    int B = in_sizes[0] / D;               // 32768

    float* colsum = (float*)d_ws;                    // [1024]
    float* dvec   = colsum + D;                      // [128]
    char*  Vstage = (char*)d_ws + 8192;              // 64 x 16KB = 1 MB

    hipMemsetAsync(colsum, 0, D * sizeof(float), stream);

    vconv_kernel<<<(KTOT * KOUT) / 256, 256, 0, stream>>>(V, Vstage);

    const int rows_per_block = 128;
    colsum_kernel<<<B / rows_per_block, 256, 0, stream>>>(e1, e2, colsum, rows_per_block);
    diag_kernel<<<KOUT, 256, 0, stream>>>(W, b, colsum, dvec,
                                          1.0f / ((float)D * (float)B));
    mfma_gemm_tanh<<<B / BM, 256, 0, stream>>>(e1, e2, Vstage, dvec, out);
}

// Round 4
// 144.476 us; speedup vs baseline: 2.1615x; 1.1427x over previous
//
#include <hip/hip_runtime.h>
#include <stdint.h>

#define D 1024
#define KOUT 128
#define KTOT 2048
#define BM 64
#define NSTEPS 64

typedef __attribute__((ext_vector_type(8))) __bf16 bf16x8;
typedef __attribute__((ext_vector_type(4))) float f32x4;

// ---------------- Kernel A: colsum[j] = sum_b e1[b,j]*e2[b,j] ----------------
// Grid = 16 col-stripes x 128 row-chunks = 2048 blocks (8/CU, 32 waves/CU).
// Block: 256 rows x 64 cols; full unroll, 2 accumulators; LDS tree-reduce;
// 16 threads/block do the atomics (128 atomics per colsum address total).
__global__ __launch_bounds__(256) void colsum_kernel(
    const float* __restrict__ e1, const float* __restrict__ e2,
    float* __restrict__ colsum) {
    int tid = threadIdx.x;
    int stripe = blockIdx.x & 15;          // column stripe (64 floats = 16 float4)
    int chunk  = blockIdx.x >> 4;          // row chunk (256 rows)
    int c4   = tid & 15;                   // float4-col within stripe
    int rloc = tid >> 4;                   // 0..15
    long row0 = (long)chunk * 256;
    int col4 = stripe * 16 + c4;           // global float4 column (0..255)

    const float4* e1v = (const float4*)e1;
    const float4* e2v = (const float4*)e2;
    const int cols4 = D / 4;               // 256

    float4 s0 = {0.f, 0.f, 0.f, 0.f};
    float4 s1 = {0.f, 0.f, 0.f, 0.f};
    #pragma unroll
    for (int p = 0; p < 16; p += 2) {
        long i0 = (row0 + (p + 0) * 16 + rloc) * cols4 + col4;
        long i1 = (row0 + (p + 1) * 16 + rloc) * cols4 + col4;
        float4 a0 = e1v[i0], b0 = e2v[i0];
        float4 a1 = e1v[i1], b1 = e2v[i1];
        s0.x += a0.x * b0.x; s0.y += a0.y * b0.y;
        s0.z += a0.z * b0.z; s0.w += a0.w * b0.w;
        s1.x += a1.x * b1.x; s1.y += a1.y * b1.y;
        s1.z += a1.z * b1.z; s1.w += a1.w * b1.w;
    }
    s0.x += s1.x; s0.y += s1.y; s0.z += s1.z; s0.w += s1.w;

    __shared__ float4 red[256];
    red[tid] = s0;
    __syncthreads();
    if (tid < 128) {
        float4 o = red[tid + 128];
        red[tid].x += o.x; red[tid].y += o.y; red[tid].z += o.z; red[tid].w += o.w;
    }
    __syncthreads();
    if (tid < 64) {
        float4 o = red[tid + 64];
        red[tid].x += o.x; red[tid].y += o.y; red[tid].z += o.z; red[tid].w += o.w;
    }
    __syncthreads();
    if (tid < 32) {
        float4 o = red[tid + 32];
        red[tid].x += o.x; red[tid].y += o.y; red[tid].z += o.z; red[tid].w += o.w;
    }
    __syncthreads();
    if (tid < 16) {
        float4 o = red[tid + 16];
        float4 r = red[tid];
        r.x += o.x; r.y += o.y; r.z += o.z; r.w += o.w;
        atomicAdd(&colsum[col4 * 4 + 0], r.x);
        atomicAdd(&colsum[col4 * 4 + 1], r.y);
        atomicAdd(&colsum[col4 * 4 + 2], r.z);
        atomicAdd(&colsum[col4 * 4 + 3], r.w);
    }
}

// ---------------- Kernel B: dvec[i] = b[i] + (1/(d*B)) * sum_j W[i,j]*colsum[j]
__global__ __launch_bounds__(256) void diag_kernel(
    const float* __restrict__ W, const float* __restrict__ bias,
    const float* __restrict__ colsum, float* __restrict__ dvec, float inv_scale) {
    int i = blockIdx.x;
    int tid = threadIdx.x;
    float s = 0.f;
    for (int j = tid; j < D; j += 256) s += W[i * D + j] * colsum[j];
    #pragma unroll
    for (int off = 32; off > 0; off >>= 1) s += __shfl_down(s, off, 64);
    __shared__ float wsum[4];
    if ((tid & 63) == 0) wsum[tid >> 6] = s;
    __syncthreads();
    if (tid == 0)
        dvec[i] = bias[i] + (wsum[0] + wsum[1] + wsum[2] + wsum[3]) * inv_scale;
}

// ---------------- Kernel V: build staging-ready, pre-swizzled hi/lo split of V
__global__ __launch_bounds__(256) void vconv_kernel(
    const float* __restrict__ V, char* __restrict__ Vstage) {
    int idx = blockIdx.x * 256 + threadIdx.x;   // over 2048*128 elements of V[k][n]
    int k = idx >> 7;
    int n = idx & 127;
    float x = V[idx];
    __bf16 h = (__bf16)x;
    __bf16 l = (__bf16)(x - (float)h);
    int kstep = k >> 5;
    int kk = k & 31;
    uint32_t sw = ((uint32_t)(n & 7)) << 4;
    uint32_t oh = (uint32_t)(n * 128 + kk * 2);
    char* base = Vstage + (size_t)kstep * 16384;
    *(__bf16*)(base + (oh ^ sw)) = h;
    *(__bf16*)(base + ((oh + 64) ^ sw)) = l;
}

// ---------------- Kernel C: out = tanh([e1|e2] @ V + dvec), LDS-staged MFMA ----
__global__ __launch_bounds__(256) void mfma_gemm_tanh(
    const float* __restrict__ e1, const float* __restrict__ e2,
    const char* __restrict__ Vstage, const float* __restrict__ dvec,
    float* __restrict__ out) {
    __shared__ char As[2][8192];
    __shared__ char Bs[2][16384];

    int tid  = threadIdx.x;
    int wave = tid >> 6;
    int lane = tid & 63;
    int lrow = lane & 15;
    int lk   = lane >> 4;                  // 0..3
    long m0  = (long)blockIdx.x * BM;

    f32x4 acc[8];
    #pragma unroll
    for (int ct = 0; ct < 8; ++ct) acc[ct] = (f32x4){0.f, 0.f, 0.f, 0.f};

    auto stage = [&](int s, int buf) {
        const float* src = (s < 32) ? e1 : e2;
        int kc = (s & 31) * 32;            // float column offset
        #pragma unroll
        for (int r = 0; r < 2; ++r) {
            uint32_t slot = (uint32_t)(r * 4096 + tid * 16);
            uint32_t row  = slot >> 7;
            uint32_t o    = slot ^ ((row & 7u) << 4);
            const char* g = (const char*)src + (((long)(m0 + row)) << 12)
                            + (kc << 2) + (o & 127u);
            char* l = &As[buf][r * 4096 + wave * 1024];
            __builtin_amdgcn_global_load_lds(
                (const __attribute__((address_space(1))) uint32_t*)g,
                (__attribute__((address_space(3))) uint32_t*)l, 16, 0, 0);
        }
        const char* gb = Vstage + (size_t)s * 16384;
        #pragma unroll
        for (int r = 0; r < 4; ++r) {
            const char* g = gb + r * 4096 + tid * 16;
            char* l = &Bs[buf][r * 4096 + wave * 1024];
            __builtin_amdgcn_global_load_lds(
                (const __attribute__((address_space(1))) uint32_t*)g,
                (__attribute__((address_space(3))) uint32_t*)l, 16, 0, 0);
        }
    };

    stage(0, 0);
    __syncthreads();

    uint32_t arow = (uint32_t)(wave * 16 + lrow);
    uint32_t asw  = (arow & 7u) << 4;
    uint32_t aoff = (uint32_t)(arow * 128 + lk * 32);
    uint32_t a0off = (aoff) ^ asw;
    uint32_t a1off = (aoff + 16) ^ asw;

    for (int s = 0; s < NSTEPS; ++s) {
        int cur = s & 1;
        if (s + 1 < NSTEPS) stage(s + 1, cur ^ 1);

        const char* ab = &As[cur][0];
        f32x4 a0 = *(const f32x4*)(ab + a0off);
        f32x4 a1 = *(const f32x4*)(ab + a1off);

        bf16x8 ah, al;
        #pragma unroll
        for (int j = 0; j < 4; ++j) {
            float x = a0[j];
            __bf16 h = (__bf16)x;
            ah[j] = h;
            al[j] = (__bf16)(x - (float)h);
            float y = a1[j];
            __bf16 h2 = (__bf16)y;
            ah[4 + j] = h2;
            al[4 + j] = (__bf16)(y - (float)h2);
        }

        const char* bb = &Bs[cur][0];
        #pragma unroll
        for (int ct = 0; ct < 8; ++ct) {
            uint32_t n = (uint32_t)(ct * 16 + lrow);
            uint32_t boff = (n * 128 + (uint32_t)(lk * 16)) ^ ((n & 7u) << 4);
            bf16x8 bh = *(const bf16x8*)(bb + boff);
            bf16x8 bl = *(const bf16x8*)(bb + (boff ^ 64u));
            acc[ct] = __builtin_amdgcn_mfma_f32_16x16x32_bf16(ah, bh, acc[ct], 0, 0, 0);
            acc[ct] = __builtin_amdgcn_mfma_f32_16x16x32_bf16(al, bh, acc[ct], 0, 0, 0);
            acc[ct] = __builtin_amdgcn_mfma_f32_16x16x32_bf16(ah, bl, acc[ct], 0, 0, 0);
        }
        __syncthreads();
    }

    // ---- epilogue: + dvec, tanh, store (D frag: col=lane&15, row=(lane>>4)*4+v)
    #pragma unroll
    for (int ct = 0; ct < 8; ++ct) {
        float dv = dvec[ct * 16 + lrow];
        #pragma unroll
        for (int v = 0; v < 4; ++v) {
            long row = m0 + wave * 16 + lk * 4 + v;
            out[row * KOUT + ct * 16 + lrow] = tanhf(acc[ct][v] + dv);
        }
    }
}

extern "C" void kernel_launch(void* const* d_in, const int* in_sizes, int n_in,
                              void* d_out, int out_size, void* d_ws, size_t ws_size,
                              hipStream_t stream) {
    const float* e1 = (const float*)d_in[0];
    const float* e2 = (const float*)d_in[1];
    const float* W  = (const float*)d_in[2];
    const float* V  = (const float*)d_in[3];
    const float* b  = (const float*)d_in[4];
    float* out = (float*)d_out;

    int B = in_sizes[0] / D;               // 32768

    float* colsum = (float*)d_ws;                    // [1024]
    float* dvec   = colsum + D;                      // [128]
    char*  Vstage = (char*)d_ws + 8192;              // 64 x 16KB = 1 MB

    hipMemsetAsync(colsum, 0, D * sizeof(float), stream);

    vconv_kernel<<<(KTOT * KOUT) / 256, 256, 0, stream>>>(V, Vstage);

    colsum_kernel<<<(B / 256) * 16, 256, 0, stream>>>(e1, e2, colsum);
    diag_kernel<<<KOUT, 256, 0, stream>>>(W, b, colsum, dvec,
                                          1.0f / ((float)D * (float)B));
    mfma_gemm_tanh<<<B / BM, 256, 0, stream>>>(e1, e2, Vstage, dvec, out);
}

// Round 5
// 143.896 us; speedup vs baseline: 2.1702x; 1.0040x over previous
//
#include <hip/hip_runtime.h>
#include <stdint.h>

#define D 1024
#define KOUT 128
#define BM 64
#define NSTEPS 64

typedef __attribute__((ext_vector_type(8))) __bf16 bf16x8;
typedef __attribute__((ext_vector_type(4))) float f32x4;

// ---------------- diag: dvec[i] = b[i] + (1/(d*B)) * sum_j W[i,j]*colsum[j] ----
__global__ __launch_bounds__(256) void diag_kernel(
    const float* __restrict__ W, const float* __restrict__ bias,
    const float* __restrict__ colsum, float* __restrict__ dvec, float inv_scale) {
    int i = blockIdx.x;
    int tid = threadIdx.x;
    float s = 0.f;
    for (int j = tid; j < D; j += 256) s += W[i * D + j] * colsum[j];
    #pragma unroll
    for (int off = 32; off > 0; off >>= 1) s += __shfl_down(s, off, 64);
    __shared__ float wsum[4];
    if ((tid & 63) == 0) wsum[tid >> 6] = s;
    __syncthreads();
    if (tid == 0)
        dvec[i] = bias[i] + (wsum[0] + wsum[1] + wsum[2] + wsum[3]) * inv_scale;
}

// ---------------- vconv: staging-ready, pre-swizzled hi/lo split of V ----------
__global__ __launch_bounds__(256) void vconv_kernel(
    const float* __restrict__ V, char* __restrict__ Vstage) {
    int idx = blockIdx.x * 256 + threadIdx.x;   // over 2048*128 elements of V[k][n]
    int k = idx >> 7;
    int n = idx & 127;
    float x = V[idx];
    __bf16 h = (__bf16)x;
    __bf16 l = (__bf16)(x - (float)h);
    int kstep = k >> 5;
    int kk = k & 31;
    uint32_t sw = ((uint32_t)(n & 7)) << 4;
    uint32_t oh = (uint32_t)(n * 128 + kk * 2);
    char* base = Vstage + (size_t)kstep * 16384;
    *(__bf16*)(base + (oh ^ sw)) = h;
    *(__bf16*)(base + ((oh + 64) ^ sw)) = l;
}

// ---------------- fused GEMM + colsum --------------------------------------
// K-step order: s even -> e1 cols [t*32,t*32+32), s odd -> e2 same cols
// (t = s>>1); B-tile index bt = (s&1)*32 + t. Accumulation order-invariant.
// Pipeline: A triple-buffered (prefetch depth 2), B double-buffered (depth 1).
// Per-iter issue order: stage_B(s+1) THEN stage_A(s+2); end-of-iter
// s_waitcnt vmcnt(2) leaves exactly A(s+2) in flight (FIFO semantics),
// so A(s+1)+B(s+1) are complete; raw s_barrier (no implicit drain).
__global__ __launch_bounds__(256) void mfma_gemm_fused(
    const float* __restrict__ e1, const float* __restrict__ e2,
    const char* __restrict__ Vstage, float* __restrict__ ff,
    float* __restrict__ colsum) {
    __shared__ char As[3][8192];
    __shared__ char Bs[2][16384];
    __shared__ float cs[1024];

    int tid  = threadIdx.x;
    int wave = tid >> 6;
    int lane = tid & 63;
    int lrow = lane & 15;
    int lk   = lane >> 4;                  // 0..3
    long m0  = (long)blockIdx.x * BM;

    for (int i = tid; i < 1024; i += 256) cs[i] = 0.f;

    f32x4 acc[8];
    #pragma unroll
    for (int ct = 0; ct < 8; ++ct) acc[ct] = (f32x4){0.f, 0.f, 0.f, 0.f};

    auto stage_A = [&](int s, int buf) {
        int ss = s & 63;
        const float* src = (ss & 1) ? e2 : e1;
        int kcb = (ss >> 1) << 7;          // byte col offset = t*32 floats
        #pragma unroll
        for (int r = 0; r < 2; ++r) {
            uint32_t slot = (uint32_t)(r * 4096 + tid * 16);
            uint32_t row  = slot >> 7;
            uint32_t o    = slot ^ ((row & 7u) << 4);
            const char* g = (const char*)src + (((long)(m0 + row)) << 12)
                            + kcb + (o & 127u);
            char* l = &As[buf][r * 4096 + wave * 1024];
            __builtin_amdgcn_global_load_lds(
                (const __attribute__((address_space(1))) uint32_t*)g,
                (__attribute__((address_space(3))) uint32_t*)l, 16, 0, 0);
        }
    };
    auto stage_B = [&](int s, int buf) {
        int ss = s & 63;
        int bt = ((ss & 1) << 5) + (ss >> 1);
        const char* gb = Vstage + (size_t)bt * 16384;
        #pragma unroll
        for (int r = 0; r < 4; ++r) {
            const char* g = gb + r * 4096 + tid * 16;
            char* l = &Bs[buf][r * 4096 + wave * 1024];
            __builtin_amdgcn_global_load_lds(
                (const __attribute__((address_space(1))) uint32_t*)g,
                (__attribute__((address_space(3))) uint32_t*)l, 16, 0, 0);
        }
    };

    // prologue: FIFO = B(0),A(0),A(1); vmcnt(2) waits B(0)+A(0), leaves A(1)
    stage_B(0, 0);
    stage_A(0, 0);
    stage_A(1, 1);
    asm volatile("s_waitcnt vmcnt(2)" ::: "memory");
    __builtin_amdgcn_s_barrier();
    __builtin_amdgcn_sched_barrier(0);

    uint32_t arow = (uint32_t)(wave * 16 + lrow);
    uint32_t asw  = (arow & 7u) << 4;
    uint32_t a0off = (arow * 128 + lk * 32) ^ asw;
    uint32_t a1off = (arow * 128 + lk * 32 + 16) ^ asw;

    f32x4 pe0 = {0.f, 0.f, 0.f, 0.f}, pe1 = {0.f, 0.f, 0.f, 0.f};
    int cA = 0;                            // buf of step s (s % 3)
    for (int s = 0; s < NSTEPS; ++s) {
        stage_B(s + 1, (s + 1) & 1);
        int c2 = cA + 2; if (c2 >= 3) c2 -= 3;
        stage_A(s + 2, c2);

        const char* ab = &As[cA][0];
        f32x4 a0 = *(const f32x4*)(ab + a0off);
        f32x4 a1 = *(const f32x4*)(ab + a1off);

        bf16x8 ah, al;
        #pragma unroll
        for (int j = 0; j < 4; ++j) {
            float x = a0[j];
            __bf16 h = (__bf16)x;
            ah[j] = h;
            al[j] = (__bf16)(x - (float)h);
            float y = a1[j];
            __bf16 h2 = (__bf16)y;
            ah[4 + j] = h2;
            al[4 + j] = (__bf16)(y - (float)h2);
        }

        const char* bb = &Bs[s & 1][0];
        #pragma unroll
        for (int ct = 0; ct < 8; ++ct) {
            uint32_t n = (uint32_t)(ct * 16 + lrow);
            uint32_t boff = (n * 128 + (uint32_t)(lk * 16)) ^ ((n & 7u) << 4);
            bf16x8 bh = *(const bf16x8*)(bb + boff);
            bf16x8 bl = *(const bf16x8*)(bb + (boff ^ 64u));
            acc[ct] = __builtin_amdgcn_mfma_f32_16x16x32_bf16(ah, bh, acc[ct], 0, 0, 0);
            acc[ct] = __builtin_amdgcn_mfma_f32_16x16x32_bf16(al, bh, acc[ct], 0, 0, 0);
            acc[ct] = __builtin_amdgcn_mfma_f32_16x16x32_bf16(ah, bl, acc[ct], 0, 0, 0);
        }

        // ---- fused colsum: pair (e1 step, e2 step) share coords
        if ((s & 1) == 0) {
            pe0 = a0; pe1 = a1;
        } else {
            float p[8];
            #pragma unroll
            for (int j = 0; j < 4; ++j) {
                p[j]     = pe0[j] * a0[j];
                p[4 + j] = pe1[j] * a1[j];
            }
            #pragma unroll
            for (int m = 1; m <= 8; m <<= 1)
                #pragma unroll
                for (int j = 0; j < 8; ++j)
                    p[j] += __shfl_xor(p[j], m, 64);
            if (lrow == 0) {
                int cb = (s >> 1) * 32 + lk * 8;
                #pragma unroll
                for (int j = 0; j < 8; ++j)
                    atomicAdd(&cs[cb + j], p[j]);
            }
        }

        asm volatile("s_waitcnt vmcnt(2)" ::: "memory");
        __builtin_amdgcn_s_barrier();
        __builtin_amdgcn_sched_barrier(0);
        cA = (cA == 2) ? 0 : cA + 1;
    }

    // ---- store pre-activation ff (D frag: col=lane&15, row=(lane>>4)*4+v)
    #pragma unroll
    for (int ct = 0; ct < 8; ++ct)
        #pragma unroll
        for (int v = 0; v < 4; ++v) {
            long row = m0 + wave * 16 + lk * 4 + v;
            ff[row * KOUT + ct * 16 + lrow] = acc[ct][v];
        }

    __syncthreads();
    for (int i = tid; i < 1024; i += 256) atomicAdd(&colsum[i], cs[i]);
}

// ---------------- epilogue: out = tanh(ff + dvec), in place -------------------
__global__ __launch_bounds__(256) void epilogue_kernel(
    float* __restrict__ io, const float* __restrict__ dvec) {
    __shared__ float dv[KOUT];
    if (threadIdx.x < KOUT) dv[threadIdx.x] = dvec[threadIdx.x];
    __syncthreads();
    int t = blockIdx.x * 256 + threadIdx.x;        // 0..524287
    float4* io4 = (float4*)io;
    #pragma unroll
    for (int h = 0; h < 2; ++h) {
        int i = t + h * 524288;
        float4 v = io4[i];
        int c = (i & 31) * 4;
        v.x = tanhf(v.x + dv[c + 0]);
        v.y = tanhf(v.y + dv[c + 1]);
        v.z = tanhf(v.z + dv[c + 2]);
        v.w = tanhf(v.w + dv[c + 3]);
        io4[i] = v;
    }
}

extern "C" void kernel_launch(void* const* d_in, const int* in_sizes, int n_in,
                              void* d_out, int out_size, void* d_ws, size_t ws_size,
                              hipStream_t stream) {
    const float* e1 = (const float*)d_in[0];
    const float* e2 = (const float*)d_in[1];
    const float* W  = (const float*)d_in[2];
    const float* V  = (const float*)d_in[3];
    const float* b  = (const float*)d_in[4];
    float* out = (float*)d_out;

    int B = in_sizes[0] / D;               // 32768

    float* colsum = (float*)d_ws;                    // [1024]
    float* dvec   = colsum + D;                      // [128]
    char*  Vstage = (char*)d_ws + 8192;              // 64 x 16KB = 1 MB

    hipMemsetAsync(colsum, 0, D * sizeof(float), stream);

    vconv_kernel<<<(2 * D * KOUT) / 256, 256, 0, stream>>>(V, Vstage);

    // fused GEMM writes pre-activation ff into d_out and accumulates colsum
    mfma_gemm_fused<<<B / BM, 256, 0, stream>>>(e1, e2, Vstage, out, colsum);
    diag_kernel<<<KOUT, 256, 0, stream>>>(W, b, colsum, dvec,
                                          1.0f / ((float)D * (float)B));
    epilogue_kernel<<<(B * KOUT) / (256 * 8), 256, 0, stream>>>(out, dvec);
}

// Round 6
// 129.916 us; speedup vs baseline: 2.4037x; 1.1076x over previous
//
#include <hip/hip_runtime.h>
#include <stdint.h>

#define D 1024
#define KOUT 128
#define BM 64
#define NSTEPS 64

typedef __attribute__((ext_vector_type(8))) __bf16 bf16x8;
typedef __attribute__((ext_vector_type(4))) float f32x4;

// DPP row_ror add: v += rotate_within_16(v, N). Rows of 16 consecutive lanes.
template <int CTRL>
__device__ __forceinline__ float dpp_ror_add(float v) {
    int t = __builtin_amdgcn_update_dpp(
        0, __builtin_bit_cast(int, v), CTRL, 0xf, 0xf, true);
    return v + __builtin_bit_cast(float, t);
}

// ---------------- diag: dvec[i] = b[i] + (1/(d*B)) * sum_j W[i,j]*colsum[j] ----
__global__ __launch_bounds__(256) void diag_kernel(
    const float* __restrict__ W, const float* __restrict__ bias,
    const float* __restrict__ colsum, float* __restrict__ dvec, float inv_scale) {
    int i = blockIdx.x;
    int tid = threadIdx.x;
    float s = 0.f;
    for (int j = tid; j < D; j += 256) s += W[i * D + j] * colsum[j];
    #pragma unroll
    for (int off = 32; off > 0; off >>= 1) s += __shfl_down(s, off, 64);
    __shared__ float wsum[4];
    if ((tid & 63) == 0) wsum[tid >> 6] = s;
    __syncthreads();
    if (tid == 0)
        dvec[i] = bias[i] + (wsum[0] + wsum[1] + wsum[2] + wsum[3]) * inv_scale;
}

// ---------------- vconv: staging-ready, pre-swizzled hi/lo split of V ----------
__global__ __launch_bounds__(256) void vconv_kernel(
    const float* __restrict__ V, char* __restrict__ Vstage) {
    int idx = blockIdx.x * 256 + threadIdx.x;   // over 2048*128 elements of V[k][n]
    int k = idx >> 7;
    int n = idx & 127;
    float x = V[idx];
    __bf16 h = (__bf16)x;
    __bf16 l = (__bf16)(x - (float)h);
    int kstep = k >> 5;
    int kk = k & 31;
    uint32_t sw = ((uint32_t)(n & 7)) << 4;
    uint32_t oh = (uint32_t)(n * 128 + kk * 2);
    char* base = Vstage + (size_t)kstep * 16384;
    *(__bf16*)(base + (oh ^ sw)) = h;
    *(__bf16*)(base + ((oh + 64) ^ sw)) = l;
}

// ---------------- fused GEMM + colsum --------------------------------------
// K-step order: s even -> e1 cols [t*32,t*32+32), s odd -> e2 same cols
// (t = s>>1). A triple-buffered (depth 2), B double-buffered (depth 1).
// Per-iter: issue B(s+1) then A(s+2); end-of-iter s_waitcnt vmcnt(2) leaves
// exactly A(s+2)'s 2 loads in flight (FIFO), then raw s_barrier (no drain).
// Fused colsum: even step latches a0/a1; odd step multiplies (same coords),
// DPP row_ror tree reduces over the 16-lane row group, 4 lanes/wave do LDS
// atomics.  NO sched_barrier anywhere (m141 lesson).
__global__ __launch_bounds__(256) void mfma_gemm_fused(
    const float* __restrict__ e1, const float* __restrict__ e2,
    const char* __restrict__ Vstage, float* __restrict__ ff,
    float* __restrict__ colsum) {
    __shared__ char As[3][8192];
    __shared__ char Bs[2][16384];
    __shared__ float cs[1024];

    int tid  = threadIdx.x;
    int wave = tid >> 6;
    int lane = tid & 63;
    int lrow = lane & 15;
    int lk   = lane >> 4;                  // 0..3
    long m0  = (long)blockIdx.x * BM;

    for (int i = tid; i < 1024; i += 256) cs[i] = 0.f;

    f32x4 acc[8];
    #pragma unroll
    for (int ct = 0; ct < 8; ++ct) acc[ct] = (f32x4){0.f, 0.f, 0.f, 0.f};

    auto stage_A = [&](int s, int buf) {
        int ss = s & 63;
        const float* src = (ss & 1) ? e2 : e1;
        int kcb = (ss >> 1) << 7;          // byte col offset = t*32 floats
        #pragma unroll
        for (int r = 0; r < 2; ++r) {
            uint32_t slot = (uint32_t)(r * 4096 + tid * 16);
            uint32_t row  = slot >> 7;
            uint32_t o    = slot ^ ((row & 7u) << 4);
            const char* g = (const char*)src + (((long)(m0 + row)) << 12)
                            + kcb + (o & 127u);
            char* l = &As[buf][r * 4096 + wave * 1024];
            __builtin_amdgcn_global_load_lds(
                (const __attribute__((address_space(1))) uint32_t*)g,
                (__attribute__((address_space(3))) uint32_t*)l, 16, 0, 0);
        }
    };
    auto stage_B = [&](int s, int buf) {
        int ss = s & 63;
        int bt = ((ss & 1) << 5) + (ss >> 1);
        const char* gb = Vstage + (size_t)bt * 16384;
        #pragma unroll
        for (int r = 0; r < 4; ++r) {
            const char* g = gb + r * 4096 + tid * 16;
            char* l = &Bs[buf][r * 4096 + wave * 1024];
            __builtin_amdgcn_global_load_lds(
                (const __attribute__((address_space(1))) uint32_t*)g,
                (__attribute__((address_space(3))) uint32_t*)l, 16, 0, 0);
        }
    };

    // prologue: FIFO = B(0)x4, A(0)x2, A(1)x2; vmcnt(2) -> B(0),A(0) done
    stage_B(0, 0);
    stage_A(0, 0);
    stage_A(1, 1);
    asm volatile("s_waitcnt vmcnt(2)" ::: "memory");
    __builtin_amdgcn_s_barrier();

    uint32_t arow = (uint32_t)(wave * 16 + lrow);
    uint32_t asw  = (arow & 7u) << 4;
    uint32_t a0off = (arow * 128 + lk * 32) ^ asw;
    uint32_t a1off = (arow * 128 + lk * 32 + 16) ^ asw;

    f32x4 pe0 = {0.f, 0.f, 0.f, 0.f}, pe1 = {0.f, 0.f, 0.f, 0.f};
    int cA = 0;                            // buf of step s (s % 3)
    for (int s = 0; s < NSTEPS; ++s) {
        stage_B(s + 1, (s + 1) & 1);
        int c2 = cA + 2; if (c2 >= 3) c2 -= 3;
        stage_A(s + 2, c2);

        const char* ab = &As[cA][0];
        f32x4 a0 = *(const f32x4*)(ab + a0off);
        f32x4 a1 = *(const f32x4*)(ab + a1off);

        bf16x8 ah, al;
        #pragma unroll
        for (int j = 0; j < 4; ++j) {
            float x = a0[j];
            __bf16 h = (__bf16)x;
            ah[j] = h;
            al[j] = (__bf16)(x - (float)h);
            float y = a1[j];
            __bf16 h2 = (__bf16)y;
            ah[4 + j] = h2;
            al[4 + j] = (__bf16)(y - (float)h2);
        }

        const char* bb = &Bs[s & 1][0];
        #pragma unroll
        for (int ct = 0; ct < 8; ++ct) {
            uint32_t n = (uint32_t)(ct * 16 + lrow);
            uint32_t boff = (n * 128 + (uint32_t)(lk * 16)) ^ ((n & 7u) << 4);
            bf16x8 bh = *(const bf16x8*)(bb + boff);
            bf16x8 bl = *(const bf16x8*)(bb + (boff ^ 64u));
            acc[ct] = __builtin_amdgcn_mfma_f32_16x16x32_bf16(ah, bh, acc[ct], 0, 0, 0);
            acc[ct] = __builtin_amdgcn_mfma_f32_16x16x32_bf16(al, bh, acc[ct], 0, 0, 0);
            acc[ct] = __builtin_amdgcn_mfma_f32_16x16x32_bf16(ah, bl, acc[ct], 0, 0, 0);
        }

        // ---- fused colsum: (e1 step, e2 step) pairs share coords
        if ((s & 1) == 0) {
            pe0 = a0; pe1 = a1;
        } else {
            float p[8];
            #pragma unroll
            for (int j = 0; j < 4; ++j) {
                p[j]     = pe0[j] * a0[j];
                p[4 + j] = pe1[j] * a1[j];
            }
            // DPP tree over the 16-lane row group (pure VALU)
            #pragma unroll
            for (int j = 0; j < 8; ++j) {
                p[j] = dpp_ror_add<0x121>(p[j]);   // row_ror:1
                p[j] = dpp_ror_add<0x122>(p[j]);   // row_ror:2
                p[j] = dpp_ror_add<0x124>(p[j]);   // row_ror:4
                p[j] = dpp_ror_add<0x128>(p[j]);   // row_ror:8
            }
            if (lrow == 0) {
                int cb = (s >> 1) * 32 + lk * 8;
                #pragma unroll
                for (int j = 0; j < 8; ++j)
                    atomicAdd(&cs[cb + j], p[j]);
            }
        }

        asm volatile("s_waitcnt vmcnt(2)" ::: "memory");
        __builtin_amdgcn_s_barrier();
        cA = (cA == 2) ? 0 : cA + 1;
    }

    // ---- store pre-activation ff (D frag: col=lane&15, row=(lane>>4)*4+v)
    #pragma unroll
    for (int ct = 0; ct < 8; ++ct)
        #pragma unroll
        for (int v = 0; v < 4; ++v) {
            long row = m0 + wave * 16 + lk * 4 + v;
            ff[row * KOUT + ct * 16 + lrow] = acc[ct][v];
        }

    __syncthreads();
    for (int i = tid; i < 1024; i += 256) atomicAdd(&colsum[i], cs[i]);
}

// ---------------- epilogue: out = tanh(ff + dvec), in place -------------------
__global__ __launch_bounds__(256) void epilogue_kernel(
    float* __restrict__ io, const float* __restrict__ dvec) {
    __shared__ float dv[KOUT];
    if (threadIdx.x < KOUT) dv[threadIdx.x] = dvec[threadIdx.x];
    __syncthreads();
    int t = blockIdx.x * 256 + threadIdx.x;        // 0..524287
    float4* io4 = (float4*)io;
    #pragma unroll
    for (int h = 0; h < 2; ++h) {
        int i = t + h * 524288;
        float4 v = io4[i];
        int c = (i & 31) * 4;
        v.x = tanhf(v.x + dv[c + 0]);
        v.y = tanhf(v.y + dv[c + 1]);
        v.z = tanhf(v.z + dv[c + 2]);
        v.w = tanhf(v.w + dv[c + 3]);
        io4[i] = v;
    }
}

extern "C" void kernel_launch(void* const* d_in, const int* in_sizes, int n_in,
                              void* d_out, int out_size, void* d_ws, size_t ws_size,
                              hipStream_t stream) {
    const float* e1 = (const float*)d_in[0];
    const float* e2 = (const float*)d_in[1];
    const float* W  = (const float*)d_in[2];
    const float* V  = (const float*)d_in[3];
    const float* b  = (const float*)d_in[4];
    float* out = (float*)d_out;

    int B = in_sizes[0] / D;               // 32768

    float* colsum = (float*)d_ws;                    // [1024]
    float* dvec   = colsum + D;                      // [128]
    char*  Vstage = (char*)d_ws + 8192;              // 64 x 16KB = 1 MB

    hipMemsetAsync(colsum, 0, D * sizeof(float), stream);

    vconv_kernel<<<(2 * D * KOUT) / 256, 256, 0, stream>>>(V, Vstage);

    // fused GEMM writes pre-activation ff into d_out and accumulates colsum
    mfma_gemm_fused<<<B / BM, 256, 0, stream>>>(e1, e2, Vstage, out, colsum);
    diag_kernel<<<KOUT, 256, 0, stream>>>(W, b, colsum, dvec,
                                          1.0f / ((float)D * (float)B));
    epilogue_kernel<<<(B * KOUT) / (256 * 8), 256, 0, stream>>>(out, dvec);
}